// Round 1
// baseline (710.383 us; speedup 1.0000x reference)
//
#include <hip/hip_runtime.h>
#include <hip/hip_bf16.h>
#include <math.h>

// Problem constants (from reference): B=16, S=256 -> N=4096 tokens; D=256; U=2000.
#define N_TOK 4096
#define DIM   256

// One wave (64 threads) per token. Lane t owns output columns [4t, 4t+3].
// Per d-iteration the wave reads one full row of trans[u] as 64 x float4
// = 1 KB, perfectly coalesced. x[n,:] is staged in LDS and broadcast
// (same-address LDS read across lanes = conflict-free).
__global__ __launch_bounds__(64) void source_bias_seq_kernel(
    const float* __restrict__ inp,    // [N, D]
    const int*   __restrict__ urls,   // [N]
    const float* __restrict__ trans,  // [U, D, D]  (d_in, d_out)
    const float* __restrict__ bias,   // [U, D]
    float*       __restrict__ out)    // [N, D]
{
    const int n = blockIdx.x;
    const int t = threadIdx.x;  // 0..63

    const int u = urls[n];

    __shared__ float xs[DIM];
    // Stage x[n,:]: 64 threads x float4
    const float4 xv = reinterpret_cast<const float4*>(inp + (size_t)n * DIM)[t];
    reinterpret_cast<float4*>(xs)[t] = xv;
    __syncthreads();

    const float4* T4 = reinterpret_cast<const float4*>(
                           trans + (size_t)u * DIM * DIM) + t;
    float4 acc = reinterpret_cast<const float4*>(bias + (size_t)u * DIM)[t];

#pragma unroll 8
    for (int d = 0; d < DIM; ++d) {
        const float  x  = xs[d];
        const float4 tv = T4[(size_t)d * (DIM / 4)];
        acc.x = fmaf(x, tv.x, acc.x);
        acc.y = fmaf(x, tv.y, acc.y);
        acc.z = fmaf(x, tv.z, acc.z);
        acc.w = fmaf(x, tv.w, acc.w);
    }

    float4 o;
    o.x = tanhf(acc.x);
    o.y = tanhf(acc.y);
    o.z = tanhf(acc.z);
    o.w = tanhf(acc.w);
    reinterpret_cast<float4*>(out + (size_t)n * DIM)[t] = o;
}

extern "C" void kernel_launch(void* const* d_in, const int* in_sizes, int n_in,
                              void* d_out, int out_size, void* d_ws, size_t ws_size,
                              hipStream_t stream) {
    const float* inp   = (const float*)d_in[0];  // [B,S,D] f32
    const int*   urls  = (const int*)  d_in[1];  // [B,S]   i32
    const float* trans = (const float*)d_in[2];  // [U,D,D] f32
    const float* bias  = (const float*)d_in[3];  // [U,D]   f32
    float*       out   = (float*)d_out;

    source_bias_seq_kernel<<<N_TOK, 64, 0, stream>>>(inp, urls, trans, bias, out);
}